// Round 4
// baseline (371.939 us; speedup 1.0000x reference)
//
#include <hip/hip_runtime.h>
#include <math.h>

// Problem constants (B,N,K,C,H,W) = (2,8,8,256,96,96)
constexpr int Bc = 2, Nc = 8, Kc = 8, Cc = 256, HWc = 96 * 96;   // HW = 9216
constexpr int BN = Bc * Nc;                                       // 16
constexpr int HW2 = HWc / 2;                                      // 4608 float2
constexpr float ALPHA = 0.3f;
constexpr float SIM_HIGH = 0.8f, SIM_LOW = 0.3f;
constexpr int TILES = 144;             // 32 float2 positions per block
                                       // grid = 16*144 = 2304 = 9*256 CUs

// ---------------- reduction helpers ----------------------------------------
__device__ __forceinline__ float wred_sum_all(float v) {   // butterfly, all lanes
#pragma unroll
  for (int o = 32; o > 0; o >>= 1) v += __shfl_xor(v, o, 64);
  return v;
}
__device__ __forceinline__ float wred_sum(float v) {
#pragma unroll
  for (int o = 32; o > 0; o >>= 1) v += __shfl_down(v, o, 64);
  return v;
}
__device__ __forceinline__ float wred_max(float v) {
#pragma unroll
  for (int o = 32; o > 0; o >>= 1) v = fmaxf(v, __shfl_down(v, o, 64));
  return v;
}
__device__ __forceinline__ float bred_sum(float v, float* sc) {
  int lane = threadIdx.x & 63, wid = threadIdx.x >> 6;
  v = wred_sum(v);
  __syncthreads();
  if (lane == 0) sc[wid] = v;
  __syncthreads();
  return sc[0] + sc[1] + sc[2] + sc[3];
}
__device__ __forceinline__ float bred_max(float v, float* sc) {
  int lane = threadIdx.x & 63, wid = threadIdx.x >> 6;
  v = wred_max(v);
  __syncthreads();
  if (lane == 0) sc[wid] = v;
  __syncthreads();
  return fmaxf(fmaxf(sc[0], sc[1]), fmaxf(sc[2], sc[3]));
}

// ---------------- K1: per-(b,n,c) sums of value/value*mask + mask sum ------
__global__ __launch_bounds__(256) void k1_sums(const float* __restrict__ value,
                                               const float* __restrict__ mask,
                                               float* __restrict__ sum_v,
                                               float* __restrict__ sum_vm,
                                               float* __restrict__ msum) {
  const int bnc = blockIdx.x;      // (b*N+n)*C + c
  const int bn = bnc >> 8;
  const int tid = threadIdx.x;
  const float4* v4 = (const float4*)(value + (size_t)bnc * HWc);
  const float4* m4 = (const float4*)(mask + (size_t)bn * HWc);
  float av = 0.f, avm = 0.f, am = 0.f;
#pragma unroll
  for (int i = 0; i < 9; ++i) {              // 9*256*4 = 9216
    float4 v = v4[i * 256 + tid];
    float4 m = m4[i * 256 + tid];
    av += v.x + v.y + v.z + v.w;
    avm += v.x * m.x + v.y * m.y + v.z * m.z + v.w * m.w;
    am += (m.x + m.y) + (m.z + m.w);
  }
  __shared__ float sc[12];
  float rv = wred_sum(av);
  float rvm = wred_sum(avm);
  float rm = wred_sum(am);
  int lane = tid & 63, wid = tid >> 6;
  if (lane == 0) { sc[wid] = rv; sc[4 + wid] = rvm; sc[8 + wid] = rm; }
  __syncthreads();
  if (tid == 0) {
    sum_v[bnc] = sc[0] + sc[1] + sc[2] + sc[3];
    sum_vm[bnc] = sc[4] + sc[5] + sc[6] + sc[7];
    if ((bnc & 255) == 0)                     // one block per bn writes msum
      msum[bn] = sc[8] + sc[9] + sc[10] + sc[11];
  }
}

// ---------------- K3: fused control logic + readout ------------------------
// Grid doubled vs round-3 (2304 = 9 blocks/CU exactly, zero tail) by
// halving the position tile to 32 float2. Within a wave: h = lane>>5 picks
// channel parity, p = lane&31 the position; step c0 loads channels
// w*64+2c0 (lanes 0-31) and +1 (lanes 32-63) -> two aligned 256B segments
// per instruction (full-line coverage, no write amplification).
// pn broadcast via __shfl(rC[k], h*32+c0) (per-lane bpermute index);
// parity halves folded with shfl_xor(32) before the 9.2KB cross-wave
// reduce. LDS union 9.3KB -> 8 blocks/CU wave-capped.
__global__ __launch_bounds__(256, 8) void k3_fused(
    const float* __restrict__ value, const float* __restrict__ frame,
    const float* __restrict__ mask_unused, const float* __restrict__ proto,
    const float* __restrict__ age, const float* __restrict__ usage,
    const float* __restrict__ conf, const int* __restrict__ valid,
    const float* __restrict__ sum_v, const float* __restrict__ sum_vm,
    const float* __restrict__ msum, const float* __restrict__ pgp,
    const float* __restrict__ fgp, float* __restrict__ out) {
  const int bn = blockIdx.x / TILES;
  const int tile = blockIdx.x % TILES;
  const int b = bn >> 3;
  const int tid = threadIdx.x;
  const int lane = tid & 63, w = tid >> 6;
  const int h = lane >> 5;                   // channel parity of this lane
  const int p = lane & 31;                   // position within tile
  const int p2 = tile * 32 + p;              // float2 index within HW2
  const int hbase = h << 5;                  // shfl base for pn broadcast

  __shared__ union {
    struct { float cand[Cc]; float pn[Kc * Cc]; float sim[Kc]; } pre;  // 9248B
    float part[4 * 9 * 64];                  // [w][8 dots + ss][32 float2]
  } u;
  __shared__ float sc[4];
  __shared__ float s_binv[Kc], s_vld[Kc];
  __shared__ int s_slot, s_ref, s_wr;

  // ======================= preamble: k2 logic ==============================
  // (1) global maxima for age_n / usage_n (over all B,N,K = 128 values)
  float a = (tid < BN * Kc) ? age[tid] : -3e38f;
  float uu = (tid < BN * Kc) ? usage[tid] : -3e38f;
  const float age_den = fmaxf(bred_max(a, sc), 1.0f);
  const float usage_den = fmaxf(bred_max(uu, sc), 1.0f);

  // (2) mask sum comes precomputed from k1
  const float denom = fmaxf(msum[bn], 1e-6f);

  // (3) candidate prototype (c = tid), l2-normalized
  const float sv = sum_v[bn * Cc + tid];
  const float svm = sum_vm[bn * Cc + tid];
  float cand = (denom <= 1e-5f) ? (sv * (1.0f / HWc)) : (svm / denom);
  const float css = bred_sum(cand * cand, sc);
  u.pre.cand[tid] = cand / fmaxf(sqrtf(css), 1e-12f);
  __syncthreads();

  const float4 c4 = ((const float4*)u.pre.cand)[lane];

  // (4) sims: wave w handles k = w, w+4; keep proto fragments in registers
  float4 p4k[2];
#pragma unroll
  for (int kk = 0; kk < 2; ++kk) {
    const int k = w + kk * 4;
    p4k[kk] = ((const float4*)(proto + ((size_t)bn * Kc + k) * Cc))[lane];
    const float4 p4 = p4k[kk];
    const float pss = wred_sum_all(p4.x * p4.x + p4.y * p4.y + p4.z * p4.z + p4.w * p4.w);
    const float pd  = wred_sum_all(p4.x * c4.x + p4.y * c4.y + p4.z * c4.z + p4.w * c4.w);
    if (lane == 0)
      u.pre.sim[k] = (valid[bn * Kc + k] != 0) ? (pd / fmaxf(sqrtf(pss), 1e-12f)) : -1.0f;
  }
  __syncthreads();

  // (5) serial decision
  if (tid == 0) {
    bool anyv = false;
    for (int k = 0; k < Kc; ++k) anyv = anyv || (valid[bn * Kc + k] != 0);
    int tslot = 0; float best = u.pre.sim[0];
    for (int k = 1; k < Kc; ++k)
      if (u.pre.sim[k] > best) { best = u.pre.sim[k]; tslot = k; }   // first max
    const float max_sim = anyv ? best : -1.0f;
    const int action = (!anyv) ? 3 : (max_sim >= SIM_HIGH ? 1 : (max_sim >= SIM_LOW ? 0 : 3));
    int victim = 0; float vb = -3e38f;
    for (int k = 0; k < Kc; ++k) {
      const float s = age[bn * Kc + k] / age_den + (1.f - usage[bn * Kc + k] / usage_den) +
                      (1.f - conf[bn * Kc + k]);
      if (s > vb) { vb = s; victim = k; }
    }
    int fe = 0; bool hasE = false;
    for (int k = 0; k < Kc; ++k)
      if (valid[bn * Kc + k] == 0) { fe = k; hasE = true; break; }
    const int spawn = hasE ? fe : victim;
    s_slot = (action == 1) ? tslot : spawn;
    s_ref = (action == 1);
    s_wr = (action == 3);
  }
  __syncthreads();

  // (6) bank update into LDS pn-table + per-k inverse norm + validity
#pragma unroll
  for (int kk = 0; kk < 2; ++kk) {
    const int k = w + kk * 4;
    const float4 p4 = p4k[kk];
    float4 pn;
    if (k == s_slot && s_ref) {
      float4 t;
      t.x = (1.0f - ALPHA) * p4.x + ALPHA * c4.x;
      t.y = (1.0f - ALPHA) * p4.y + ALPHA * c4.y;
      t.z = (1.0f - ALPHA) * p4.z + ALPHA * c4.z;
      t.w = (1.0f - ALPHA) * p4.w + ALPHA * c4.w;
      const float tss = wred_sum_all(t.x * t.x + t.y * t.y + t.z * t.z + t.w * t.w);
      const float inv = 1.0f / fmaxf(sqrtf(tss), 1e-12f);
      pn.x = t.x * inv; pn.y = t.y * inv; pn.z = t.z * inv; pn.w = t.w * inv;
    } else if (k == s_slot && s_wr) {
      pn = c4;
    } else {
      pn = p4;
    }
    ((float4*)(u.pre.pn + k * Cc))[lane] = pn;
    const float bss = wred_sum_all(pn.x * pn.x + pn.y * pn.y + pn.z * pn.z + pn.w * pn.w);
    if (lane == 0) s_binv[k] = 1.0f / fmaxf(sqrtf(bss), 1e-12f);
  }
  if (tid < Kc)
    s_vld[tid] = ((valid[bn * Kc + tid] != 0) || (s_wr && tid == s_slot)) ? 1.0f : 0.0f;
  __syncthreads();

  // (7) lane's pn fragment: rC[k] = pn[k][w*64 + 2p + h]  (2-way LDS, free)
  float rC[8], binv[8], vld[8];
#pragma unroll
  for (int k = 0; k < 8; ++k) {
    rC[k] = u.pre.pn[k * Cc + w * 64 + 2 * p + h];
    binv[k] = s_binv[k];
    vld[k] = s_vld[k];
  }
  __syncthreads();                               // u.part may now be written

  // ========================== main readout =================================
  const float pg = pgp[0], fg = fgp[0];
  const float2* v2 = (const float2*)(value + (size_t)bn * Cc * HWc);
  const float2* f2 = (const float2*)(frame + (size_t)b * Cc * HWc);
  float2* o2 = (float2*)(out + (size_t)bn * Cc * HWc);

  // ---- pass 1: dots + ||v||^2 over this lane's 32 channels (parity h) -----
  float ss0 = 0.f, ss1 = 0.f;
  float d0[8], d1[8];
#pragma unroll
  for (int k = 0; k < 8; ++k) { d0[k] = 0.f; d1[k] = 0.f; }

#pragma unroll 8
  for (int c0 = 0; c0 < 32; ++c0) {
    const int c = w * 64 + 2 * c0 + h;
    const float2 v = v2[(size_t)c * HW2 + p2];   // 2x256B aligned segments
    ss0 += v.x * v.x; ss1 += v.y * v.y;
#pragma unroll
    for (int k = 0; k < 8; ++k) {
      const float pk = __shfl(rC[k], hbase + c0, 64);   // bpermute broadcast
      d0[k] += pk * v.x;
      d1[k] += pk * v.y;
    }
  }

  // fold the two parity halves (lane bit 5)
#pragma unroll
  for (int k = 0; k < 8; ++k) {
    d0[k] += __shfl_xor(d0[k], 32, 64);
    d1[k] += __shfl_xor(d1[k], 32, 64);
  }
  ss0 += __shfl_xor(ss0, 32, 64);
  ss1 += __shfl_xor(ss1, 32, 64);

  float2* sp2 = (float2*)u.part;
  if (h == 0) {
#pragma unroll
    for (int k = 0; k < 8; ++k)
      sp2[(w * 9 + k) * 32 + p] = make_float2(d0[k], d1[k]);
    sp2[(w * 9 + 8) * 32 + p] = make_float2(ss0, ss1);
  }
  __syncthreads();

  // ---- cross-wave reduce + softmax (redundant on both halves) -------------
  float a0[8], a1[8];
  {
    float dd0[9], dd1[9];
#pragma unroll
    for (int j = 0; j < 9; ++j) {
      const float2 t0 = sp2[(0 * 9 + j) * 32 + p];   // l and l+32 same addr:
      const float2 t1 = sp2[(1 * 9 + j) * 32 + p];   // broadcast, conflict-free
      const float2 t2 = sp2[(2 * 9 + j) * 32 + p];
      const float2 t3 = sp2[(3 * 9 + j) * 32 + p];
      dd0[j] = (t0.x + t1.x) + (t2.x + t3.x);
      dd1[j] = (t0.y + t1.y) + (t2.y + t3.y);
    }
    const float rn0 = 1.0f / fmaxf(sqrtf(dd0[8]), 1e-12f);
    const float rn1 = 1.0f / fmaxf(sqrtf(dd1[8]), 1e-12f);
    float m0 = -3e38f, m1 = -3e38f;
#pragma unroll
    for (int k = 0; k < 8; ++k) {
      const float scl = binv[k];                  // bank norm as scalar
      dd0[k] *= scl * rn0;
      dd1[k] *= scl * rn1;
      if (vld[k] > 0.5f) { m0 = fmaxf(m0, dd0[k]); m1 = fmaxf(m1, dd1[k]); }
    }
    float sum0 = 0.f, sum1 = 0.f;
#pragma unroll
    for (int k = 0; k < 8; ++k) {
      a0[k] = (vld[k] > 0.5f) ? __expf(dd0[k] - m0) : 0.f;
      a1[k] = (vld[k] > 0.5f) ? __expf(dd1[k] - m1) : 0.f;
      sum0 += a0[k]; sum1 += a1[k];
    }
    const float i0 = (sum0 > 0.f) ? 1.0f / sum0 : 0.f;   // no valid -> attn 0
    const float i1 = (sum1 > 0.f) ? 1.0f / sum1 : 0.f;
#pragma unroll
    for (int k = 0; k < 8; ++k) { a0[k] *= i0; a1[k] *= i1; }
  }

  // ---- pass 2: blend this lane's 32 channels (re-read is L3-hot) ----------
#pragma unroll 4
  for (int c0 = 0; c0 < 32; ++c0) {
    const int c = w * 64 + 2 * c0 + h;
    const size_t off = (size_t)c * HW2 + p2;
    const float2 v = v2[off];
    const float2 f = f2[off];
    float pm0 = 0.f, pm1 = 0.f;
#pragma unroll
    for (int k = 0; k < 8; ++k) {
      const float pk = __shfl(rC[k], hbase + c0, 64);
      pm0 += a0[k] * pk;
      pm1 += a1[k] * pk;
    }
    float2 o;
    o.x = v.x + pg * pm0 + fg * f.x;
    o.y = v.y + pg * pm1 + fg * f.y;
    o2[off] = o;                                  // 2x256B aligned segments
  }
}

// ---------------- launch ---------------------------------------------------
extern "C" void kernel_launch(void* const* d_in, const int* in_sizes, int n_in,
                              void* d_out, int out_size, void* d_ws, size_t ws_size,
                              hipStream_t stream) {
  const float* value = (const float*)d_in[0];
  const float* frame = (const float*)d_in[1];
  const float* mask  = (const float*)d_in[2];
  const float* proto = (const float*)d_in[3];
  const float* age   = (const float*)d_in[4];
  const float* usage = (const float*)d_in[5];
  const float* conf  = (const float*)d_in[6];
  // d_in[7..10] = W1,b1,W2,b2 — dead code in the reference (logits unused)
  const float* pg = (const float*)d_in[11];
  const float* fg = (const float*)d_in[12];
  const int* valid = (const int*)d_in[13];
  float* out = (float*)d_out;

  float* w = (float*)d_ws;
  float* sum_v  = w;                     // BN*Cc = 4096
  float* sum_vm = w + 4096;              // BN*Cc = 4096
  float* msum   = w + 8192;              // BN    = 16

  hipLaunchKernelGGL(k1_sums, dim3(BN * Cc), dim3(256), 0, stream,
                     value, mask, sum_v, sum_vm, msum);
  hipLaunchKernelGGL(k3_fused, dim3(BN * TILES), dim3(256), 0, stream,
                     value, frame, mask, proto, age, usage, conf, valid,
                     sum_v, sum_vm, msum, pg, fg, out);
}

// Round 6
// 352.826 us; speedup vs baseline: 1.0542x; 1.0542x over previous
//
#include <hip/hip_runtime.h>
#include <math.h>

// Problem constants (B,N,K,C,H,W) = (2,8,8,256,96,96)
constexpr int Bc = 2, Nc = 8, Kc = 8, Cc = 256, HWc = 96 * 96;   // HW = 9216
constexpr int BN = Bc * Nc;                                       // 16
constexpr int HW2 = HWc / 2;                                      // 4608 float2
constexpr float ALPHA = 0.3f;
constexpr float SIM_HIGH = 0.8f, SIM_LOW = 0.3f;
constexpr int TILES = 72;              // 64 float2 positions per block

typedef float nfloat2 __attribute__((ext_vector_type(2)));  // native vec2 for
                                                            // nontemporal store

// ---------------- reduction helpers ----------------------------------------
__device__ __forceinline__ float wred_sum_all(float v) {   // butterfly, all lanes
#pragma unroll
  for (int o = 32; o > 0; o >>= 1) v += __shfl_xor(v, o, 64);
  return v;
}
__device__ __forceinline__ float wred_sum(float v) {
#pragma unroll
  for (int o = 32; o > 0; o >>= 1) v += __shfl_down(v, o, 64);
  return v;
}
__device__ __forceinline__ float wred_max(float v) {
#pragma unroll
  for (int o = 32; o > 0; o >>= 1) v = fmaxf(v, __shfl_down(v, o, 64));
  return v;
}
__device__ __forceinline__ float bred_sum(float v, float* sc) {
  int lane = threadIdx.x & 63, wid = threadIdx.x >> 6;
  v = wred_sum(v);
  __syncthreads();
  if (lane == 0) sc[wid] = v;
  __syncthreads();
  return sc[0] + sc[1] + sc[2] + sc[3];
}
__device__ __forceinline__ float bred_max(float v, float* sc) {
  int lane = threadIdx.x & 63, wid = threadIdx.x >> 6;
  v = wred_max(v);
  __syncthreads();
  if (lane == 0) sc[wid] = v;
  __syncthreads();
  return fmaxf(fmaxf(sc[0], sc[1]), fmaxf(sc[2], sc[3]));
}

// ---------------- K1: per-(b,n,c) sums of value/value*mask + mask sum ------
__global__ __launch_bounds__(256) void k1_sums(const float* __restrict__ value,
                                               const float* __restrict__ mask,
                                               float* __restrict__ sum_v,
                                               float* __restrict__ sum_vm,
                                               float* __restrict__ msum) {
  const int bnc = blockIdx.x;      // (b*N+n)*C + c
  const int bn = bnc >> 8;
  const int tid = threadIdx.x;
  const float4* v4 = (const float4*)(value + (size_t)bnc * HWc);
  const float4* m4 = (const float4*)(mask + (size_t)bn * HWc);
  float av = 0.f, avm = 0.f, am = 0.f;
#pragma unroll
  for (int i = 0; i < 9; ++i) {              // 9*256*4 = 9216
    float4 v = v4[i * 256 + tid];
    float4 m = m4[i * 256 + tid];
    av += v.x + v.y + v.z + v.w;
    avm += v.x * m.x + v.y * m.y + v.z * m.z + v.w * m.w;
    am += (m.x + m.y) + (m.z + m.w);
  }
  __shared__ float sc[12];
  float rv = wred_sum(av);
  float rvm = wred_sum(avm);
  float rm = wred_sum(am);
  int lane = tid & 63, wid = tid >> 6;
  if (lane == 0) { sc[wid] = rv; sc[4 + wid] = rvm; sc[8 + wid] = rm; }
  __syncthreads();
  if (tid == 0) {
    sum_v[bnc] = sc[0] + sc[1] + sc[2] + sc[3];
    sum_vm[bnc] = sc[4] + sc[5] + sc[6] + sc[7];
    if ((bnc & 255) == 0)                     // one block per bn writes msum
      msum[bn] = sc[8] + sc[9] + sc[10] + sc[11];
  }
}

// ---------------- K3: fused control logic + readout ------------------------
// Round-3 geometry (the proven best): wave w owns channels [64w,64w+64) for
// the same 64 float2 positions; 512B-coalesced global accesses; 1152 blocks.
// Round-5/6 changes: pn broadcast via wave-uniform ds_read_b128 of a
// channel-major [c][k] LDS table (2 LDS ops/c0 replace 8 readlane VALU ops;
// uniform address -> broadcast, conflict-free), built once by an LDS
// transpose in the preamble; non-temporal stores for out (dead-on-write,
// stop evicting value from L3 between pass1 and pass2); pass2 unroll 8.
// LDS = union(preamble 9.2KB | s_part 18.4KB) + pn_c 8KB ~= 26.7KB
// -> 5 blocks/CU >= the 4.5 the grid supplies.
__global__ __launch_bounds__(256, 8) void k3_fused(
    const float* __restrict__ value, const float* __restrict__ frame,
    const float* __restrict__ mask_unused, const float* __restrict__ proto,
    const float* __restrict__ age, const float* __restrict__ usage,
    const float* __restrict__ conf, const int* __restrict__ valid,
    const float* __restrict__ sum_v, const float* __restrict__ sum_vm,
    const float* __restrict__ msum, const float* __restrict__ pgp,
    const float* __restrict__ fgp, float* __restrict__ out) {
  const int bn = blockIdx.x / TILES;
  const int tile = blockIdx.x % TILES;
  const int b = bn >> 3;
  const int tid = threadIdx.x;
  const int lane = tid & 63, w = tid >> 6;
  const int p2 = tile * 64 + lane;           // float2 index within HW2

  __shared__ union {
    struct { float cand[Cc]; float pn[Kc * Cc]; float sim[Kc]; } pre;  // 9248B
    float part[4 * 9 * 128];                 // [w][8 dots + ss][64 float2]
  } u;
  __shared__ float s_pnc[Cc * Kc];           // [c][k] channel-major, 8KB
  __shared__ float sc[4];
  __shared__ float s_binv[Kc], s_vld[Kc];
  __shared__ int s_slot, s_ref, s_wr;

  // ======================= preamble: k2 logic ==============================
  // (1) global maxima for age_n / usage_n (over all B,N,K = 128 values)
  float a = (tid < BN * Kc) ? age[tid] : -3e38f;
  float uu = (tid < BN * Kc) ? usage[tid] : -3e38f;
  const float age_den = fmaxf(bred_max(a, sc), 1.0f);
  const float usage_den = fmaxf(bred_max(uu, sc), 1.0f);

  // (2) mask sum comes precomputed from k1
  const float denom = fmaxf(msum[bn], 1e-6f);

  // (3) candidate prototype (c = tid), l2-normalized
  const float sv = sum_v[bn * Cc + tid];
  const float svm = sum_vm[bn * Cc + tid];
  float cand = (denom <= 1e-5f) ? (sv * (1.0f / HWc)) : (svm / denom);
  const float css = bred_sum(cand * cand, sc);
  u.pre.cand[tid] = cand / fmaxf(sqrtf(css), 1e-12f);
  __syncthreads();

  const float4 c4 = ((const float4*)u.pre.cand)[lane];

  // (4) sims: wave w handles k = w, w+4; keep proto fragments in registers
  float4 p4k[2];
#pragma unroll
  for (int kk = 0; kk < 2; ++kk) {
    const int k = w + kk * 4;
    p4k[kk] = ((const float4*)(proto + ((size_t)bn * Kc + k) * Cc))[lane];
    const float4 p4 = p4k[kk];
    const float pss = wred_sum_all(p4.x * p4.x + p4.y * p4.y + p4.z * p4.z + p4.w * p4.w);
    const float pd  = wred_sum_all(p4.x * c4.x + p4.y * c4.y + p4.z * c4.z + p4.w * c4.w);
    if (lane == 0)
      u.pre.sim[k] = (valid[bn * Kc + k] != 0) ? (pd / fmaxf(sqrtf(pss), 1e-12f)) : -1.0f;
  }
  __syncthreads();

  // (5) serial decision
  if (tid == 0) {
    bool anyv = false;
    for (int k = 0; k < Kc; ++k) anyv = anyv || (valid[bn * Kc + k] != 0);
    int tslot = 0; float best = u.pre.sim[0];
    for (int k = 1; k < Kc; ++k)
      if (u.pre.sim[k] > best) { best = u.pre.sim[k]; tslot = k; }   // first max
    const float max_sim = anyv ? best : -1.0f;
    const int action = (!anyv) ? 3 : (max_sim >= SIM_HIGH ? 1 : (max_sim >= SIM_LOW ? 0 : 3));
    int victim = 0; float vb = -3e38f;
    for (int k = 0; k < Kc; ++k) {
      const float s = age[bn * Kc + k] / age_den + (1.f - usage[bn * Kc + k] / usage_den) +
                      (1.f - conf[bn * Kc + k]);
      if (s > vb) { vb = s; victim = k; }
    }
    int fe = 0; bool hasE = false;
    for (int k = 0; k < Kc; ++k)
      if (valid[bn * Kc + k] == 0) { fe = k; hasE = true; break; }
    const int spawn = hasE ? fe : victim;
    s_slot = (action == 1) ? tslot : spawn;
    s_ref = (action == 1);
    s_wr = (action == 3);
  }
  __syncthreads();

  // (6) bank update into LDS pn-table (k-major) + per-k inv norm + validity
#pragma unroll
  for (int kk = 0; kk < 2; ++kk) {
    const int k = w + kk * 4;
    const float4 p4 = p4k[kk];
    float4 pn;
    if (k == s_slot && s_ref) {
      float4 t;
      t.x = (1.0f - ALPHA) * p4.x + ALPHA * c4.x;
      t.y = (1.0f - ALPHA) * p4.y + ALPHA * c4.y;
      t.z = (1.0f - ALPHA) * p4.z + ALPHA * c4.z;
      t.w = (1.0f - ALPHA) * p4.w + ALPHA * c4.w;
      const float tss = wred_sum_all(t.x * t.x + t.y * t.y + t.z * t.z + t.w * t.w);
      const float inv = 1.0f / fmaxf(sqrtf(tss), 1e-12f);
      pn.x = t.x * inv; pn.y = t.y * inv; pn.z = t.z * inv; pn.w = t.w * inv;
    } else if (k == s_slot && s_wr) {
      pn = c4;
    } else {
      pn = p4;
    }
    ((float4*)(u.pre.pn + k * Cc))[lane] = pn;
    const float bss = wred_sum_all(pn.x * pn.x + pn.y * pn.y + pn.z * pn.z + pn.w * pn.w);
    if (lane == 0) s_binv[k] = 1.0f / fmaxf(sqrtf(bss), 1e-12f);
  }
  if (tid < Kc)
    s_vld[tid] = ((valid[bn * Kc + tid] != 0) || (s_wr && tid == s_slot)) ? 1.0f : 0.0f;
  __syncthreads();

  // (7) transpose pn to channel-major [c][k] (one-time) + scalars to regs
  {
    float t[8];
#pragma unroll
    for (int k = 0; k < 8; ++k) t[k] = u.pre.pn[k * Cc + tid];   // 2 lanes/bank
    float4* d = (float4*)(s_pnc + tid * 8);
    d[0] = make_float4(t[0], t[1], t[2], t[3]);                  // 16-way, once
    d[1] = make_float4(t[4], t[5], t[6], t[7]);
  }
  float binv[8], vld[8];
#pragma unroll
  for (int k = 0; k < 8; ++k) { binv[k] = s_binv[k]; vld[k] = s_vld[k]; }
  __syncthreads();                             // u.part may now be written

  // ========================== main readout =================================
  const float pg = pgp[0], fg = fgp[0];
  const float2* v2 = (const float2*)(value + (size_t)bn * Cc * HWc);
  const float2* f2 = (const float2*)(frame + (size_t)b * Cc * HWc);
  nfloat2* o2 = (nfloat2*)(out + (size_t)bn * Cc * HWc);
  const float4* pnc4 = (const float4*)s_pnc;

  // ---- pass 1: dots + ||v||^2 over this wave's 64 channels ----------------
  float ss0 = 0.f, ss1 = 0.f;
  float d0[8], d1[8];
#pragma unroll
  for (int k = 0; k < 8; ++k) { d0[k] = 0.f; d1[k] = 0.f; }

#pragma unroll 8
  for (int c0 = 0; c0 < 64; ++c0) {
    const int c = w * 64 + c0;
    const float2 v = v2[(size_t)c * HW2 + p2];   // 512B coalesced
    const float4 ba = pnc4[c * 2 + 0];           // uniform addr -> broadcast
    const float4 bb = pnc4[c * 2 + 1];
    ss0 += v.x * v.x; ss1 += v.y * v.y;
    d0[0] += ba.x * v.x; d0[1] += ba.y * v.x; d0[2] += ba.z * v.x; d0[3] += ba.w * v.x;
    d0[4] += bb.x * v.x; d0[5] += bb.y * v.x; d0[6] += bb.z * v.x; d0[7] += bb.w * v.x;
    d1[0] += ba.x * v.y; d1[1] += ba.y * v.y; d1[2] += ba.z * v.y; d1[3] += ba.w * v.y;
    d1[4] += bb.x * v.y; d1[5] += bb.y * v.y; d1[6] += bb.z * v.y; d1[7] += bb.w * v.y;
  }

  float2* sp2 = (float2*)u.part;
#pragma unroll
  for (int k = 0; k < 8; ++k)
    sp2[(w * 9 + k) * 64 + lane] = make_float2(d0[k], d1[k]);
  sp2[(w * 9 + 8) * 64 + lane] = make_float2(ss0, ss1);
  __syncthreads();

  // ---- cross-wave reduce + softmax (redundant on all 4 waves) -------------
  float a0[8], a1[8];
  {
    float dd0[9], dd1[9];
#pragma unroll
    for (int j = 0; j < 9; ++j) {
      const float2 t0 = sp2[(0 * 9 + j) * 64 + lane];
      const float2 t1 = sp2[(1 * 9 + j) * 64 + lane];
      const float2 t2 = sp2[(2 * 9 + j) * 64 + lane];
      const float2 t3 = sp2[(3 * 9 + j) * 64 + lane];
      dd0[j] = (t0.x + t1.x) + (t2.x + t3.x);
      dd1[j] = (t0.y + t1.y) + (t2.y + t3.y);
    }
    const float rn0 = 1.0f / fmaxf(sqrtf(dd0[8]), 1e-12f);
    const float rn1 = 1.0f / fmaxf(sqrtf(dd1[8]), 1e-12f);
    float m0 = -3e38f, m1 = -3e38f;
#pragma unroll
    for (int k = 0; k < 8; ++k) {
      const float scl = binv[k];                  // bank norm as scalar
      dd0[k] *= scl * rn0;
      dd1[k] *= scl * rn1;
      if (vld[k] > 0.5f) { m0 = fmaxf(m0, dd0[k]); m1 = fmaxf(m1, dd1[k]); }
    }
    float sum0 = 0.f, sum1 = 0.f;
#pragma unroll
    for (int k = 0; k < 8; ++k) {
      a0[k] = (vld[k] > 0.5f) ? __expf(dd0[k] - m0) : 0.f;
      a1[k] = (vld[k] > 0.5f) ? __expf(dd1[k] - m1) : 0.f;
      sum0 += a0[k]; sum1 += a1[k];
    }
    const float i0 = (sum0 > 0.f) ? 1.0f / sum0 : 0.f;   // no valid -> attn 0
    const float i1 = (sum1 > 0.f) ? 1.0f / sum1 : 0.f;
#pragma unroll
    for (int k = 0; k < 8; ++k) { a0[k] *= i0; a1[k] *= i1; }
  }

  // ---- pass 2: blend this wave's 64 channels (re-read is L3-hot) ----------
#pragma unroll 8
  for (int c0 = 0; c0 < 64; ++c0) {
    const int c = w * 64 + c0;
    const size_t off = (size_t)c * HW2 + p2;
    const float2 v = v2[off];
    const float2 f = f2[off];
    const float4 pa = pnc4[c * 2 + 0];           // uniform addr -> broadcast
    const float4 pb = pnc4[c * 2 + 1];
    const float pm0 = a0[0] * pa.x + a0[1] * pa.y + a0[2] * pa.z + a0[3] * pa.w +
                      a0[4] * pb.x + a0[5] * pb.y + a0[6] * pb.z + a0[7] * pb.w;
    const float pm1 = a1[0] * pa.x + a1[1] * pa.y + a1[2] * pa.z + a1[3] * pa.w +
                      a1[4] * pb.x + a1[5] * pb.y + a1[6] * pb.z + a1[7] * pb.w;
    nfloat2 o;
    o.x = v.x + pg * pm0 + fg * f.x;
    o.y = v.y + pg * pm1 + fg * f.y;
    __builtin_nontemporal_store(o, &o2[off]);    // dead-on-write: keep L3 for v
  }
}

// ---------------- launch ---------------------------------------------------
extern "C" void kernel_launch(void* const* d_in, const int* in_sizes, int n_in,
                              void* d_out, int out_size, void* d_ws, size_t ws_size,
                              hipStream_t stream) {
  const float* value = (const float*)d_in[0];
  const float* frame = (const float*)d_in[1];
  const float* mask  = (const float*)d_in[2];
  const float* proto = (const float*)d_in[3];
  const float* age   = (const float*)d_in[4];
  const float* usage = (const float*)d_in[5];
  const float* conf  = (const float*)d_in[6];
  // d_in[7..10] = W1,b1,W2,b2 — dead code in the reference (logits unused)
  const float* pg = (const float*)d_in[11];
  const float* fg = (const float*)d_in[12];
  const int* valid = (const int*)d_in[13];
  float* out = (float*)d_out;

  float* w = (float*)d_ws;
  float* sum_v  = w;                     // BN*Cc = 4096
  float* sum_vm = w + 4096;              // BN*Cc = 4096
  float* msum   = w + 8192;              // BN    = 16

  hipLaunchKernelGGL(k1_sums, dim3(BN * Cc), dim3(256), 0, stream,
                     value, mask, sum_v, sum_vm, msum);
  hipLaunchKernelGGL(k3_fused, dim3(BN * TILES), dim3(256), 0, stream,
                     value, frame, mask, proto, age, usage, conf, valid,
                     sum_v, sum_vm, msum, pg, fg, out);
}